// Round 3
// baseline (738.156 us; speedup 1.0000x reference)
//
#include <hip/hip_runtime.h>
#include <math.h>

#define LEAKY(x) ((x) >= 0.f ? (x) : 0.3f*(x))

// ---- workspace float offsets ----
#define G_OFF   0         // 648     extracted g~ (72x9)
#define IM_OFF  648       // 7776    im (b,ch,81)
#define LAM_OFF 8424      // 32      lambda per batch
#define WB_OFF  8456      // 2592    w branch (b,81)
#define YBR_OFF 11048     // 82944   y branch (b,81,32)
#define X1_OFF  93992     // 663552  conv51 out (b,36,36,16)
#define X2_OFF  757544    // 331776  conv15 out (b,18,18,32)
#define X3_OFF  1089320   // 165888  conv55 out (b,9,9,64)

#define OUT0 106272       // elements in output 0; cs_out follows

// ======================= prep =======================
__global__ __launch_bounds__(256) void prep_kernel(
    const float* __restrict__ inp, const float* __restrict__ mat,
    const float* __restrict__ w1_k, const float* __restrict__ w1_b,
    const float* __restrict__ x1_k, const float* __restrict__ x1_b,
    const float* __restrict__ y17_k, const float* __restrict__ y17_b,
    const float* __restrict__ y71_k, const float* __restrict__ y71_b,
    const float* __restrict__ yc_k, const float* __restrict__ yc_b,
    const float* __restrict__ d1_k, const float* __restrict__ d2_k,
    const float* __restrict__ h1_w, const float* __restrict__ h1_b,
    const float* __restrict__ h2_w, const float* __restrict__ h2_b,
    const float* __restrict__ h3_w, const float* __restrict__ h3_b,
    float* __restrict__ ws)
{
    int t = threadIdx.x;
    if (blockIdx.x == 0) {
        // extract separable factor: g[i][a] = mat[i*72, a*9] / sqrt(mat[0,0])
        float rs = rsqrtf(mat[0]);
        for (int u = t; u < 648; u += 256) {
            int i = u / 9, a = u % 9;
            ws[G_OFF + u] = mat[(size_t)(i*72)*81 + a*9] * rs;
        }
        return;
    }
    int b = blockIdx.x - 1;
    __shared__ float sin_[243];
    __shared__ float cm[27];
    __shared__ float cat[5184];
    __shared__ float z1[108];
    __shared__ float z2[24];
    __shared__ float v1[24];
    __shared__ float v2[12];

    const float BN  = 1.0f / sqrtf(1.001f);
    const float BN2 = BN * BN;

    for (int u = t; u < 243; u += 256) sin_[u] = inp[b*243 + u];
    __syncthreads();

    // w branch (t<81), colmax (81..107), d1 conv (128..235)
    if (t < 81) {
        float s = w1_b[0];
        for (int i = 0; i < 3; ++i) s += sin_[t*3+i] * w1_k[i];
        ws[WB_OFF + b*81 + t] = LEAKY(s);
    } else if (t < 108) {
        int u = t - 81;                       // c*3+ch
        float m = 0.f;
        for (int r = 0; r < 9; ++r) m = fmaxf(m, fabsf(sin_[r*27 + u]));
        cm[u] = 0.001f + m;
    }
    if (t >= 128 && t < 236) {
        int u = t - 128;                      // oy*36 + ox*12 + o
        int o = u % 12, ox = (u/12) % 3, oy = u/36;
        float s = 0.f;
        for (int kh = 0; kh < 5; ++kh) {
            int iy = oy*3 - 1 + kh;
            if (iy < 0 || iy > 8) continue;
            for (int kw = 0; kw < 5; ++kw) {
                int ix = ox*3 - 1 + kw;
                if (ix < 0 || ix > 8) continue;
                for (int i = 0; i < 3; ++i)
                    s += sin_[(iy*9+ix)*3 + i] * d1_k[((kh*5+kw)*3 + i)*12 + o];
            }
        }
        z1[u] = LEAKY(BN2 * s);
    }
    __syncthreads();

    // im = leaky(conv1x1(inp / colmax)) ; layout (b,ch,81)
    if (t < 243) {
        int o = t / 81, p = t % 81;
        int c = p % 9;
        float s = x1_b[o];
        for (int i = 0; i < 3; ++i)
            s += (sin_[p*3+i] / cm[c*3+i]) * x1_k[i*3 + o];
        ws[IM_OFF + (b*3 + o)*81 + p] = LEAKY(s);
    }
    __syncthreads();

    // d2 conv: 3x3x12 -> 1x1x24 (kernel rows/cols 1..3 valid)
    if (t < 24) {
        float s = 0.f;
        for (int kh = 1; kh < 4; ++kh)
            for (int kw = 1; kw < 4; ++kw)
                for (int i = 0; i < 12; ++i)
                    s += z1[((kh-1)*3 + (kw-1))*12 + i] * d2_k[((kh*5+kw)*12 + i)*24 + t];
        z2[t] = LEAKY(BN * s);
    }
    __syncthreads();
    if (t < 24) {
        float s = h1_b[t];
        for (int i = 0; i < 24; ++i) s += z2[i] * h1_w[i*24 + t];
        v1[t] = s;
    }
    __syncthreads();
    if (t < 12) {
        float s = h2_b[t];
        for (int i = 0; i < 24; ++i) s += v1[i] * h2_w[i*12 + t];
        v2[t] = s;
    }
    __syncthreads();
    if (t == 0) {
        float s = h3_b[0];
        for (int i = 0; i < 12; ++i) s += v2[i] * h3_w[i];
        ws[LAM_OFF + b] = 0.01f / (1.f + expf(-s));   // 0.1*sigmoid * 0.1
    }

    // y branch: cat = [y1(32) | y2(32)] per position
    for (int u = t; u < 5184; u += 256) {
        int pos = u / 64, i = u % 64;
        int r = pos / 9, c = pos % 9;
        float s;
        if (i < 32) {
            s = y17_b[i];
            for (int kw = 0; kw < 7; ++kw) {
                int cc = c - 3 + kw;
                if (cc < 0 || cc > 8) continue;
                for (int ii = 0; ii < 3; ++ii)
                    s += sin_[(r*9+cc)*3 + ii] * y17_k[(kw*3+ii)*32 + i];
            }
        } else {
            int i2 = i - 32;
            s = y71_b[i2];
            for (int kh = 0; kh < 7; ++kh) {
                int rr = r - 3 + kh;
                if (rr < 0 || rr > 8) continue;
                for (int ii = 0; ii < 3; ++ii)
                    s += sin_[(rr*9+c)*3 + ii] * y71_k[(kh*3+ii)*32 + i2];
            }
        }
        cat[pos*64 + i] = s;
    }
    __syncthreads();
    for (int u = t; u < 2592; u += 256) {
        int pos = u / 32, o = u % 32;
        float s = yc_b[o];
        for (int i = 0; i < 64; ++i) s += cat[pos*64 + i] * yc_k[i*32 + o];
        ws[YBR_OFF + (b*81 + pos)*32 + o] = LEAKY(s);
    }
}

// ======================= FISTA =======================
// 576 threads = 9 waves. t = j*8 + g: lane owns rows g*9..g*9+8 of column j.
// All intra-wave reductions on the VALU DPP pipe (zero LDS, zero barriers):
//   - over g (8 consecutive 8-aligned lanes): quad_perm xor1, xor2, half_mirror
//   - over j-pairs: row_ror:8 (= exact lane xor 8 within 16-lane rows)
// LDS is used ONLY for the cross-wave funnel:
//   A-phase reads R (6 vec reads/wave) -> qt via b-split + g-butterfly ->
//   y-update -> u g-butterfly (T on all lanes) -> sp = T*g[j][b] ->
//   ror8 fold -> 36 partial sets stored (6 vec writes/wave).  BARRIER.
//   Reduce: 324 thr, 9 strided reads + quad butterfly -> R = im - S. BARRIER.
// 2 barriers/iter, ~160 LDS wave-ops/iter (vs 293 in the 5-phase version).

#define DPP_XOR1 0xB1   // quad_perm {1,0,3,2}
#define DPP_XOR2 0x4E   // quad_perm {2,3,0,1}
#define DPP_HM   0x141  // row_half_mirror (cross-quad within 8; quads uniform)
#define DPP_ROR8 0x128  // row_ror:8 == lane xor 8 within 16-lane row

template<int CTRL>
__device__ __forceinline__ float dppadd(float v) {
    return v + __int_as_float(__builtin_amdgcn_update_dpp(
        0, __float_as_int(v), CTRL, 0xF, 0xF, true));
}

__global__ __launch_bounds__(576) void fista_kernel(
    const float* __restrict__ ws, float* __restrict__ cs_out)
{
    __shared__ __align__(16) float SPm[36*108];  // 36 sets x (9 slots x 12 pad)
    __shared__ __align__(16) float Rm[108];      // R[b][a], rows of 12

    int t = threadIdx.x;
    int b = blockIdx.x / 3, ch = blockIdx.x % 3;
    const float* g = ws + G_OFF;
    float lam = ws[LAM_OFF + b];

    int j = t >> 3, gg = t & 7;      // column j, row-group g
    int l = t & 63;                  // lane in wave

    // ---- per-thread constants in registers ----
    float Gr[81];                    // rows gg*9..gg*9+8 of G (contiguous 81)
#pragma unroll
    for (int u = 0; u < 81; ++u) Gr[u] = g[gg*81 + u];
    float Gjg = g[j*9 + gg];         // g[j][gg]
    float Gj8 = g[j*9 + 8];          // g[j][8]
    float w8  = (gg == 7) ? Gj8 : 0.f;   // b=8 qt-term counted on one lane only

    // reducer role (t < 324): ab = a*9+b pair, pp = 4-way set split
    int ab = t >> 2, pp = t & 3;
    int aa = ab / 9, bb = ab % 9;
    float im_ab = (t < 324) ? ws[IM_OFF + (b*3 + ch)*81 + ab] : 0.f;

    // init R = im (transposed: R[b][a] = im[a][b])
    if (t < 81) {
        Rm[(t % 9)*12 + (t / 9)] = ws[IM_OFF + (b*3 + ch)*81 + t];
    }

    float Yv[9], Yl[9];
#pragma unroll
    for (int s = 0; s < 9; ++s) { Yv[s] = 0.f; Yl[s] = 0.f; }
    float tk = 1.f;
    __syncthreads();

    for (int it = 0; it < 100; ++it) {
        float tn = 0.5f*(1.f + sqrtf(1.f + 4.f*tk*tk));
        float cmom = (tk - 1.f) / tn;
        tk = tn;

        // ---- qt[a] = sum_b R[a][b]*g[j][b], built by b-split + g-butterfly
        const float4* Rg4 = (const float4*)(&Rm[gg*12]);
        float4 ra = Rg4[0], rb = Rg4[1];
        float  rc = Rm[gg*12 + 8];
        const float4* R84 = (const float4*)(&Rm[96]);
        float4 sa = R84[0], sb = R84[1];
        float  sc = Rm[96 + 8];
        float qt[9];
        qt[0]=ra.x; qt[1]=ra.y; qt[2]=ra.z; qt[3]=ra.w;
        qt[4]=rb.x; qt[5]=rb.y; qt[6]=rb.z; qt[7]=rb.w; qt[8]=rc;
        float r8v[9] = {sa.x,sa.y,sa.z,sa.w,sb.x,sb.y,sb.z,sb.w,sc};
#pragma unroll
        for (int a = 0; a < 9; ++a) {
            float v = qt[a]*Gjg + r8v[a]*w8;
            v = dppadd<DPP_XOR1>(v);
            v = dppadd<DPP_XOR2>(v);
            v = dppadd<DPP_HM>(v);
            qt[a] = v;
        }

        // ---- y-update for 9 owned rows + u partials
        float uacc[9];
#pragma unroll
        for (int a = 0; a < 9; ++a) uacc[a] = 0.f;
#pragma unroll
        for (int s = 0; s < 9; ++s) {
            float re = Gr[s*9+0]*qt[0] + Gr[s*9+1]*qt[1] + Gr[s*9+2]*qt[2]
                     + Gr[s*9+3]*qt[3] + Gr[s*9+4]*qt[4] + Gr[s*9+5]*qt[5]
                     + Gr[s*9+6]*qt[6] + Gr[s*9+7]*qt[7] + Gr[s*9+8]*qt[8];
            float wv = Yv[s] + re;
            float cl = fminf(fmaxf(wv, -lam), lam);   // v_med3
            float yn = wv - cl;
            float yx = yn + cmom*(yn - Yl[s]);
            Yl[s] = yn; Yv[s] = yx;
#pragma unroll
            for (int a = 0; a < 9; ++a) uacc[a] += yx*Gr[s*9+a];
        }
        if (it == 99) break;

        // ---- T[a][j] on all lanes via g-butterfly
#pragma unroll
        for (int a = 0; a < 9; ++a) {
            float v = uacc[a];
            v = dppadd<DPP_XOR1>(v);
            v = dppadd<DPP_XOR2>(v);
            v = dppadd<DPP_HM>(v);
            uacc[a] = v;
        }

        // ---- S partials: sp[a] (b=gg), spB[a] (b=8); fold j-pairs with ror8
        float spA[9], spB[9];
#pragma unroll
        for (int a = 0; a < 9; ++a) {
            float vA = uacc[a]*Gjg;
            float vB = uacc[a]*Gj8;
            spA[a] = dppadd<DPP_ROR8>(vA);
            spB[a] = dppadd<DPP_ROR8>(vB);
        }

        // ---- store partial sets: set = wave*4 + row; slot gg (and slot 8)
        int setb = ((t >> 6)*4 + (l >> 4))*108;
        if ((l & 8) == 0) {
            float* d = &SPm[setb + gg*12];
            ((float4*)d)[0] = make_float4(spA[0],spA[1],spA[2],spA[3]);
            ((float4*)d)[1] = make_float4(spA[4],spA[5],spA[6],spA[7]);
            d[8] = spA[8];
            if (gg == 0) {
                float* d2 = &SPm[setb + 96];
                ((float4*)d2)[0] = make_float4(spB[0],spB[1],spB[2],spB[3]);
                ((float4*)d2)[1] = make_float4(spB[4],spB[5],spB[6],spB[7]);
                d2[8] = spB[8];
            }
        }
        __syncthreads();

        // ---- reduce 36 sets -> S -> R = im - S
        if (t < 324) {
            float s = 0.f;
#pragma unroll
            for (int k = 0; k < 9; ++k)
                s += SPm[(pp*9 + k)*108 + bb*12 + aa];
            s = dppadd<DPP_XOR1>(s);
            s = dppadd<DPP_XOR2>(s);
            if (pp == 0) Rm[bb*12 + aa] = im_ab - s;
        }
        __syncthreads();
    }

    // ---- output: rows gg*9+s of column j
#pragma unroll
    for (int s = 0; s < 9; ++s) {
        int i = gg*9 + s;
        cs_out[(size_t)(b*5184 + i*72 + j)*3 + ch] = Yl[s];
    }
}

// ======================= post convs =======================
__global__ __launch_bounds__(256) void c51_kernel(
    const float* __restrict__ cs, const float* __restrict__ k,
    const float* __restrict__ bias, float* __restrict__ out)
{
    int id = blockIdx.x*256 + threadIdx.x;
    if (id >= 32*36*36*16) return;
    int o = id & 15; int rest = id >> 4;
    int ox = rest % 36; rest /= 36; int oy = rest % 36; int b = rest / 36;
    float s = bias[o];
    int ix = ox*2;
    for (int kh = 0; kh < 5; ++kh) {
        int iy = oy*2 - 1 + kh;
        if (iy < 0 || iy >= 72) continue;
        const float* p = cs + ((size_t)(b*72 + iy)*72 + ix)*3;
        const float* kk = k + kh*48 + o;
        s += p[0]*kk[0] + p[1]*kk[16] + p[2]*kk[32];
    }
    out[id] = s;
}

__global__ __launch_bounds__(256) void c15_kernel(
    const float* __restrict__ x1, const float* __restrict__ k,
    const float* __restrict__ bias, float* __restrict__ out)
{
    int id = blockIdx.x*256 + threadIdx.x;
    if (id >= 32*18*18*32) return;
    int o = id & 31; int rest = id >> 5;
    int ox = rest % 18; rest /= 18; int oy = rest % 18; int b = rest / 18;
    float s = bias[o];
    int iy = oy*2;
    for (int kw = 0; kw < 5; ++kw) {
        int ix = ox*2 - 1 + kw;
        if (ix < 0 || ix >= 36) continue;
        const float* p = x1 + ((size_t)(b*36 + iy)*36 + ix)*16;
        const float* kk = k + kw*512 + o;
        for (int i = 0; i < 16; ++i) s += p[i]*kk[i*32];
    }
    out[id] = s;
}

__global__ __launch_bounds__(256) void c55_kernel(
    const float* __restrict__ x2, const float* __restrict__ k,
    const float* __restrict__ bias, float* __restrict__ out)
{
    int id = blockIdx.x*256 + threadIdx.x;
    if (id >= 32*9*9*64) return;
    int o = id & 63; int rest = id >> 6;
    int ox = rest % 9; rest /= 9; int oy = rest % 9; int b = rest / 9;
    float s = bias[o];
    for (int kh = 0; kh < 5; ++kh) {
        int iy = oy*2 - 1 + kh;
        if (iy < 0 || iy >= 18) continue;
        for (int kw = 0; kw < 5; ++kw) {
            int ix = ox*2 - 1 + kw;
            if (ix < 0 || ix >= 18) continue;
            const float* p = x2 + ((size_t)(b*18 + iy)*18 + ix)*32;
            const float* kk = k + (kh*5+kw)*2048 + o;
            for (int i = 0; i < 32; ++i) s += p[i]*kk[i*64];
        }
    }
    out[id] = s;
}

__global__ __launch_bounds__(256) void out_kernel(
    const float* __restrict__ ws, const float* __restrict__ x2_k,
    const float* __restrict__ x2_b, float* __restrict__ out)
{
    int id = blockIdx.x*256 + threadIdx.x;
    if (id >= OUT0) return;
    int q = id % 41; int rest = id / 41;
    int cc = rest % 9; rest /= 9; int r = rest % 9; int b = rest / 9;
    float val;
    if (q == 0) {
        val = ws[WB_OFF + b*81 + r*9 + cc];
    } else if (q <= 8) {
        int o = q - 1;
        const float* p = ws + X3_OFF + ((size_t)(b*9 + r)*9 + cc)*64;
        float s = x2_b[o];
        for (int i = 0; i < 64; ++i) s += p[i]*x2_k[i*8 + o];
        val = LEAKY(s);
    } else {
        val = ws[YBR_OFF + ((size_t)(b*81 + r*9 + cc))*32 + (q - 9)];
    }
    out[id] = val;
}

// ======================= launch =======================
extern "C" void kernel_launch(void* const* d_in, const int* in_sizes, int n_in,
                              void* d_out, int out_size, void* d_ws, size_t ws_size,
                              hipStream_t stream) {
    const float* inp   = (const float*)d_in[0];
    const float* mat   = (const float*)d_in[1];
    const float* w1_k  = (const float*)d_in[2];
    const float* w1_b  = (const float*)d_in[3];
    const float* x1_k  = (const float*)d_in[4];
    const float* x1_b  = (const float*)d_in[5];
    const float* c51_k = (const float*)d_in[6];
    const float* c51_b = (const float*)d_in[7];
    const float* c15_k = (const float*)d_in[8];
    const float* c15_b = (const float*)d_in[9];
    const float* c55_k = (const float*)d_in[10];
    const float* c55_b = (const float*)d_in[11];
    const float* x2_k  = (const float*)d_in[12];
    const float* x2_b  = (const float*)d_in[13];
    const float* y17_k = (const float*)d_in[14];
    const float* y17_b = (const float*)d_in[15];
    const float* y71_k = (const float*)d_in[16];
    const float* y71_b = (const float*)d_in[17];
    const float* yc_k  = (const float*)d_in[18];
    const float* yc_b  = (const float*)d_in[19];
    const float* d1_k  = (const float*)d_in[20];
    const float* d2_k  = (const float*)d_in[21];
    const float* h1_w  = (const float*)d_in[22];
    const float* h1_b  = (const float*)d_in[23];
    const float* h2_w  = (const float*)d_in[24];
    const float* h2_b  = (const float*)d_in[25];
    const float* h3_w  = (const float*)d_in[26];
    const float* h3_b  = (const float*)d_in[27];

    float* ws  = (float*)d_ws;
    float* out = (float*)d_out;
    float* cs  = out + OUT0;

    hipLaunchKernelGGL(prep_kernel, dim3(33), dim3(256), 0, stream,
        inp, mat, w1_k, w1_b, x1_k, x1_b, y17_k, y17_b, y71_k, y71_b,
        yc_k, yc_b, d1_k, d2_k, h1_w, h1_b, h2_w, h2_b, h3_w, h3_b, ws);
    hipLaunchKernelGGL(fista_kernel, dim3(96), dim3(576), 0, stream, ws, cs);
    hipLaunchKernelGGL(c51_kernel, dim3(2592), dim3(256), 0, stream, cs, c51_k, c51_b, ws + X1_OFF);
    hipLaunchKernelGGL(c15_kernel, dim3(1296), dim3(256), 0, stream, ws + X1_OFF, c15_k, c15_b, ws + X2_OFF);
    hipLaunchKernelGGL(c55_kernel, dim3(648), dim3(256), 0, stream, ws + X2_OFF, c55_k, c55_b, ws + X3_OFF);
    hipLaunchKernelGGL(out_kernel, dim3(416), dim3(256), 0, stream, ws, x2_k, x2_b, out);
}